// Round 1
// baseline (1026.043 us; speedup 1.0000x reference)
//
#include <hip/hip_runtime.h>
#include <cstdint>

// ---------------------------------------------------------------------------
// Types / helpers
// ---------------------------------------------------------------------------
typedef float floatx4 __attribute__((ext_vector_type(4)));
typedef __bf16 bf16x8 __attribute__((ext_vector_type(8)));

typedef const __attribute__((address_space(1))) void* gas_cvp;
typedef __attribute__((address_space(3))) void* las_vp;

__device__ __forceinline__ float bflo(unsigned int u) {
    return __builtin_bit_cast(float, u << 16);
}
__device__ __forceinline__ float bfhi(unsigned int u) {
    return __builtin_bit_cast(float, u & 0xffff0000u);
}
__device__ __forceinline__ unsigned short f2bf(float f) {
    unsigned int u = __builtin_bit_cast(unsigned int, f);
    u += 0x7fffu + ((u >> 16) & 1u);   // RNE (finite inputs)
    return (unsigned short)(u >> 16);
}
__device__ __forceinline__ void unpack8(uint4 u, float* f) {
    f[0] = bflo(u.x); f[1] = bfhi(u.x);
    f[2] = bflo(u.y); f[3] = bfhi(u.y);
    f[4] = bflo(u.z); f[5] = bfhi(u.z);
    f[6] = bflo(u.w); f[7] = bfhi(u.w);
}
// async global->LDS, 16B per lane. LDS dest = wave-uniform base + lane*16.
__device__ __forceinline__ void load_lds16(const void* g, void* l) {
    __builtin_amdgcn_global_load_lds(
        (gas_cvp)(unsigned long long)g,
        (las_vp)(unsigned int)(unsigned long long)l,
        16, 0, 0);
}

// ---------------------------------------------------------------------------
// f32 -> bf16 convert
// ---------------------------------------------------------------------------
__global__ void cvt_f32_bf16(const float* __restrict__ in,
                             unsigned short* __restrict__ out, int n4) {
    int i = blockIdx.x * 256 + threadIdx.x;
    if (i < n4) {
        float4 v = ((const float4*)in)[i];
        ushort4 o;
        o.x = f2bf(v.x); o.y = f2bf(v.y); o.z = f2bf(v.z); o.w = f2bf(v.w);
        ((ushort4*)out)[i] = o;
    }
}

// ---------------------------------------------------------------------------
// Generic BT GEMM:  C[m,n] = sum_k A[m,k] * B[n,k]
// A rows pass through a (rpb, bstride, roff) remap: r -> (r/rpb)*bstride + roff + r%rpb
// 128x128 tile, BK=32, 4 waves, 16x16x32 bf16 MFMA, global_load_lds staging.
// ---------------------------------------------------------------------------
struct GemmJob {
    const unsigned short* A;
    const unsigned short* B;
    void* C;
    int M, N, K;
    int rpb, bstride, roff;
};
struct GemmArgs { GemmJob j[4]; };

template <bool F32OUT>
__global__ __launch_bounds__(256, 2) void gemm_bt(GemmArgs args,
                                                  const float* __restrict__ bias) {
    GemmJob jb = args.j[blockIdx.z];
    const int bx = blockIdx.x, by = blockIdx.y;
    if (by * 128 >= jb.M) return;

    const int tid  = threadIdx.x;
    const int lane = tid & 63;
    const int wid  = tid >> 6;
    const int K = jb.K, N = jb.N;

    __shared__ unsigned short ldsA[128 * 32];
    __shared__ unsigned short ldsB[128 * 32];

    const int colA = (tid & 3) * 8;
    auto maprow = [&](int r) -> size_t {
        r = (r < jb.M) ? r : (jb.M - 1);
        int b = r / jb.rpb;
        int t = r - b * jb.rpb;
        return (size_t)(b * jb.bstride + jb.roff + t);
    };
    const unsigned short* pa0 = jb.A + maprow(by * 128 + (tid >> 2)) * K + colA;
    const unsigned short* pa1 = jb.A + maprow(by * 128 + 64 + (tid >> 2)) * K + colA;
    const unsigned short* pb0 = jb.B + (size_t)(bx * 128 + (tid >> 2)) * K + colA;
    const unsigned short* pb1 = jb.B + (size_t)(bx * 128 + 64 + (tid >> 2)) * K + colA;

    unsigned short* la0 = &ldsA[tid * 8];
    unsigned short* la1 = &ldsA[2048 + tid * 8];
    unsigned short* lb0 = &ldsB[tid * 8];
    unsigned short* lb1 = &ldsB[2048 + tid * 8];

    floatx4 acc[4][4] = {};

    const int wm = (wid & 1) * 64;
    const int wn = (wid >> 1) * 64;
    const int fr = lane & 15;
    const int fc = (lane >> 4) * 8;

    for (int k0 = 0; k0 < K; k0 += 32) {
        __syncthreads();
        load_lds16(pa0 + k0, la0);
        load_lds16(pa1 + k0, la1);
        load_lds16(pb0 + k0, lb0);
        load_lds16(pb1 + k0, lb1);
        __syncthreads();

        bf16x8 af[4], bfv[4];
#pragma unroll
        for (int i = 0; i < 4; i++)
            af[i] = *(const bf16x8*)&ldsA[(wm + i * 16 + fr) * 32 + fc];
#pragma unroll
        for (int i = 0; i < 4; i++)
            bfv[i] = *(const bf16x8*)&ldsB[(wn + i * 16 + fr) * 32 + fc];
#pragma unroll
        for (int mi = 0; mi < 4; mi++)
#pragma unroll
            for (int ni = 0; ni < 4; ni++)
                acc[mi][ni] = __builtin_amdgcn_mfma_f32_16x16x32_bf16(
                    af[mi], bfv[ni], acc[mi][ni], 0, 0, 0);
    }

    // Epilogue. C/D layout: col = lane&15, row = (lane>>4)*4 + reg (verified m89/m91).
    const int colBase = bx * 128 + wn;
    const int rowBase = by * 128 + wm;
#pragma unroll
    for (int mi = 0; mi < 4; mi++) {
#pragma unroll
        for (int ni = 0; ni < 4; ni++) {
            int col  = colBase + ni * 16 + (lane & 15);
            int row0 = rowBase + mi * 16 + (lane >> 4) * 4;
#pragma unroll
            for (int r = 0; r < 4; r++) {
                int row = row0 + r;
                if (row < jb.M) {
                    float v = acc[mi][ni][r];
                    if (F32OUT)
                        ((float*)jb.C)[(size_t)row * N + col] = v + bias[col];
                    else
                        ((unsigned short*)jb.C)[(size_t)row * N + col] = f2bf(v);
                }
            }
        }
    }
}

// ---------------------------------------------------------------------------
// Fused attention for one (batch-pair, head, 16-row q tile).
// Handles text attention for both batches, prob blend p1 <- 0.5 p1 + 0.5 p0,
// and IP attention (output added only to odd batch).
// ---------------------------------------------------------------------------
#define NTEXT 77
#define NIP 20
#define SCALE 0.125f

__global__ __launch_bounds__(256, 2) void attn_kernel(
    const unsigned short* __restrict__ q,    // [4*4096][1280]
    const unsigned short* __restrict__ kt,   // [4*77][1280]
    const unsigned short* __restrict__ vt,   // [4*77][1280]
    const unsigned short* __restrict__ kip,  // [4*20][1280]
    const unsigned short* __restrict__ vip,  // [4*20][1280]
    unsigned short* __restrict__ outp)       // [4*4096][1280]
{
    const int tid = threadIdx.x;
    const int qt = blockIdx.x;   // 0..255, 16 q rows each
    const int h  = blockIdx.y;   // 0..19
    const int p  = blockIdx.z;   // 0..1
    const int b0 = 2 * p;

    __shared__ unsigned short sQ[2][16][64];
    __shared__ unsigned short sK[2][NTEXT][64];
    __shared__ unsigned short sV[2][NTEXT][64];
    __shared__ unsigned short sKip[2][NIP][64];
    __shared__ unsigned short sVip[2][NIP][64];
    __shared__ float sP[2][16][81];   // probs scratch (text then ip), +pad

    // ---- stage Q / K / V (uint4 = 8 bf16 per load) ----
    for (int i = tid; i < 2 * 16 * 8; i += 256) {
        int bi = i >> 7, rem = i & 127;
        int r = rem >> 3, c = (rem & 7) * 8;
        size_t grow = (size_t)((b0 + bi) * 4096 + qt * 16 + r);
        *(uint4*)&sQ[bi][r][c] = *(const uint4*)&q[grow * 1280 + h * 64 + c];
    }
    for (int i = tid; i < 2 * NTEXT * 8; i += 256) {
        int bi = i / (NTEXT * 8), rem = i % (NTEXT * 8);
        int t = rem >> 3, c = (rem & 7) * 8;
        size_t src = (size_t)((b0 + bi) * NTEXT + t) * 1280 + h * 64 + c;
        *(uint4*)&sK[bi][t][c] = *(const uint4*)&kt[src];
        *(uint4*)&sV[bi][t][c] = *(const uint4*)&vt[src];
    }
    for (int i = tid; i < 2 * NIP * 8; i += 256) {
        int bi = i / (NIP * 8), rem = i % (NIP * 8);
        int t = rem >> 3, c = (rem & 7) * 8;
        size_t src = (size_t)((b0 + bi) * NIP + t) * 1280 + h * 64 + c;
        *(uint4*)&sKip[bi][t][c] = *(const uint4*)&kip[src];
        *(uint4*)&sVip[bi][t][c] = *(const uint4*)&vip[src];
    }
    __syncthreads();

    // thread mapping: oct = d-slice (8 floats), (sb,sr) = one of 32 (batch,row) slots
    const int oct = tid & 7;
    const int rowslot = tid >> 3;  // 0..31
    const int sb = rowslot >> 4;   // 0/1
    const int sr = rowslot & 15;   // 0..15

    float qf[8];
    {
        uint4 qv = *(const uint4*)&sQ[sb][sr][oct * 8];
        unpack8(qv, qf);
    }

    // ---- text scores ----
    for (int key = 0; key < NTEXT; key++) {
        uint4 kv = *(const uint4*)&sK[sb][key][oct * 8];
        float kf[8]; unpack8(kv, kf);
        float s = 0.f;
#pragma unroll
        for (int j = 0; j < 8; j++) s += qf[j] * kf[j];
        s += __shfl_xor(s, 1); s += __shfl_xor(s, 2); s += __shfl_xor(s, 4);
        if (oct == 0) sP[sb][sr][key] = s * SCALE;
    }
    __syncthreads();

    // ---- text softmax (one thread per (bi,row)) ----
    if (tid < 32) {
        int bi = tid >> 4, r = tid & 15;
        float m = -1e30f;
        for (int k = 0; k < NTEXT; k++) m = fmaxf(m, sP[bi][r][k]);
        float sum = 0.f;
        for (int k = 0; k < NTEXT; k++) {
            float e = __expf(sP[bi][r][k] - m);
            sP[bi][r][k] = e;
            sum += e;
        }
        float inv = 1.f / sum;
        for (int k = 0; k < NTEXT; k++) sP[bi][r][k] *= inv;
    }
    __syncthreads();

    // ---- blend: p1 = 0.5 p1 + 0.5 p0 ----
    for (int i = tid; i < 16 * NTEXT; i += 256) {
        int r = i / NTEXT, k = i % NTEXT;
        sP[1][r][k] = 0.5f * (sP[1][r][k] + sP[0][r][k]);
    }
    __syncthreads();

    // ---- text PV ----
    float acc[8] = {0.f, 0.f, 0.f, 0.f, 0.f, 0.f, 0.f, 0.f};
    for (int key = 0; key < NTEXT; key++) {
        float pr = sP[sb][sr][key];
        uint4 vv = *(const uint4*)&sV[sb][key][oct * 8];
        float vf[8]; unpack8(vv, vf);
#pragma unroll
        for (int j = 0; j < 8; j++) acc[j] += pr * vf[j];
    }
    __syncthreads();   // sP reads done before ip overwrites

    // ---- ip scores ----
    for (int key = 0; key < NIP; key++) {
        uint4 kv = *(const uint4*)&sKip[sb][key][oct * 8];
        float kf[8]; unpack8(kv, kf);
        float s = 0.f;
#pragma unroll
        for (int j = 0; j < 8; j++) s += qf[j] * kf[j];
        s += __shfl_xor(s, 1); s += __shfl_xor(s, 2); s += __shfl_xor(s, 4);
        if (oct == 0) sP[sb][sr][key] = s * SCALE;
    }
    __syncthreads();

    // ---- ip softmax ----
    if (tid < 32) {
        int bi = tid >> 4, r = tid & 15;
        float m = -1e30f;
        for (int k = 0; k < NIP; k++) m = fmaxf(m, sP[bi][r][k]);
        float sum = 0.f;
        for (int k = 0; k < NIP; k++) {
            float e = __expf(sP[bi][r][k] - m);
            sP[bi][r][k] = e;
            sum += e;
        }
        float inv = 1.f / sum;
        for (int k = 0; k < NIP; k++) sP[bi][r][k] *= inv;
    }
    __syncthreads();

    // ---- ip blend ----
    for (int i = tid; i < 16 * NIP; i += 256) {
        int r = i / NIP, k = i % NIP;
        sP[1][r][k] = 0.5f * (sP[1][r][k] + sP[0][r][k]);
    }
    __syncthreads();

    // ---- ip PV: only odd batch gets the ip contribution ----
    if (sb == 1) {
        for (int key = 0; key < NIP; key++) {
            float pr = sP[1][sr][key];
            uint4 vv = *(const uint4*)&sVip[1][key][oct * 8];
            float vf[8]; unpack8(vv, vf);
#pragma unroll
            for (int j = 0; j < 8; j++) acc[j] += pr * vf[j];
        }
    }

    // ---- write bf16 ----
    unsigned short ob[8];
#pragma unroll
    for (int j = 0; j < 8; j++) ob[j] = f2bf(acc[j]);
    uint4 o;
    o.x = (unsigned int)ob[0] | ((unsigned int)ob[1] << 16);
    o.y = (unsigned int)ob[2] | ((unsigned int)ob[3] << 16);
    o.z = (unsigned int)ob[4] | ((unsigned int)ob[5] << 16);
    o.w = (unsigned int)ob[6] | ((unsigned int)ob[7] << 16);
    size_t row = (size_t)((b0 + sb) * 4096 + qt * 16 + sr);
    *(uint4*)&outp[row * 1280 + h * 64 + oct * 8] = o;
}

// ---------------------------------------------------------------------------
// Host launch
// ---------------------------------------------------------------------------
extern "C" void kernel_launch(void* const* d_in, const int* in_sizes, int n_in,
                              void* d_out, int out_size, void* d_ws, size_t ws_size,
                              hipStream_t stream) {
    const float* hs   = (const float*)d_in[0];
    const float* ehs  = (const float*)d_in[1];
    const float* Wq   = (const float*)d_in[2];
    const float* Wk   = (const float*)d_in[3];
    const float* Wv   = (const float*)d_in[4];
    const float* Wkip = (const float*)d_in[5];
    const float* Wvip = (const float*)d_in[6];
    const float* Wo   = (const float*)d_in[7];
    const float* bo   = (const float*)d_in[8];

    char* w = (char*)d_ws;
    size_t off = 0;
    auto alloc = [&](size_t bytes) {
        char* pp = w + off;
        off += (bytes + 255) & ~(size_t)255;
        return pp;
    };
    unsigned short* hs_bf   = (unsigned short*)alloc(16384ull * 1280 * 2);
    unsigned short* q_bf    = (unsigned short*)alloc(16384ull * 1280 * 2);
    unsigned short* at_bf   = (unsigned short*)alloc(16384ull * 1280 * 2);
    unsigned short* ehs_bf  = (unsigned short*)alloc(4ull * 97 * 2048 * 2);
    unsigned short* Wq_bf   = (unsigned short*)alloc(1280ull * 1280 * 2);
    unsigned short* Wk_bf   = (unsigned short*)alloc(1280ull * 2048 * 2);
    unsigned short* Wv_bf   = (unsigned short*)alloc(1280ull * 2048 * 2);
    unsigned short* Wkip_bf = (unsigned short*)alloc(1280ull * 2048 * 2);
    unsigned short* Wvip_bf = (unsigned short*)alloc(1280ull * 2048 * 2);
    unsigned short* Wo_bf   = (unsigned short*)alloc(1280ull * 1280 * 2);
    unsigned short* kt  = (unsigned short*)alloc(308ull * 1280 * 2);
    unsigned short* vt  = (unsigned short*)alloc(308ull * 1280 * 2);
    unsigned short* kip = (unsigned short*)alloc(80ull * 1280 * 2);
    unsigned short* vip = (unsigned short*)alloc(80ull * 1280 * 2);

    auto cvt = [&](const float* src, unsigned short* dst, size_t n) {
        int n4 = (int)(n / 4);
        cvt_f32_bf16<<<dim3((n4 + 255) / 256), dim3(256), 0, stream>>>(src, dst, n4);
    };
    cvt(hs,   hs_bf,   16384ull * 1280);
    cvt(ehs,  ehs_bf,  4ull * 97 * 2048);
    cvt(Wq,   Wq_bf,   1280ull * 1280);
    cvt(Wk,   Wk_bf,   1280ull * 2048);
    cvt(Wv,   Wv_bf,   1280ull * 2048);
    cvt(Wkip, Wkip_bf, 1280ull * 2048);
    cvt(Wvip, Wvip_bf, 1280ull * 2048);
    cvt(Wo,   Wo_bf,   1280ull * 1280);

    // q = hs @ Wq^T
    GemmArgs gq{};
    gq.j[0] = GemmJob{hs_bf, Wq_bf, (void*)q_bf, 16384, 1280, 1280, 16384, 0, 0};
    gemm_bt<false><<<dim3(10, 128, 1), 256, 0, stream>>>(gq, nullptr);

    // k/v projections (text rows 0..76, ip rows 77..96 of each 97-row batch)
    GemmArgs gkv{};
    gkv.j[0] = GemmJob{ehs_bf, Wk_bf,   (void*)kt,  308, 1280, 2048, 77, 97, 0};
    gkv.j[1] = GemmJob{ehs_bf, Wv_bf,   (void*)vt,  308, 1280, 2048, 77, 97, 0};
    gkv.j[2] = GemmJob{ehs_bf, Wkip_bf, (void*)kip,  80, 1280, 2048, 20, 97, 77};
    gkv.j[3] = GemmJob{ehs_bf, Wvip_bf, (void*)vip,  80, 1280, 2048, 20, 97, 77};
    gemm_bt<false><<<dim3(10, 3, 4), 256, 0, stream>>>(gkv, nullptr);

    // fused attention (text + ip, blend, odd-batch ip add)
    attn_kernel<<<dim3(256, 20, 2), 256, 0, stream>>>(q_bf, kt, vt, kip, vip, at_bf);

    // out = attn @ Wo^T + bo  (f32 output)
    GemmArgs go{};
    go.j[0] = GemmJob{at_bf, Wo_bf, d_out, 16384, 1280, 1280, 16384, 0, 0};
    gemm_bt<true><<<dim3(10, 128, 1), 256, 0, stream>>>(go, bo);
}

// Round 2
// 511.277 us; speedup vs baseline: 2.0068x; 2.0068x over previous
//
#include <hip/hip_runtime.h>
#include <cstdint>

// ---------------------------------------------------------------------------
// Types / helpers
// ---------------------------------------------------------------------------
typedef float floatx4 __attribute__((ext_vector_type(4)));
typedef __bf16 bf16x8 __attribute__((ext_vector_type(8)));

typedef const __attribute__((address_space(1))) void* gas_cvp;
typedef __attribute__((address_space(3))) void* las_vp;

__device__ __forceinline__ float bflo(unsigned int u) {
    return __builtin_bit_cast(float, u << 16);
}
__device__ __forceinline__ float bfhi(unsigned int u) {
    return __builtin_bit_cast(float, u & 0xffff0000u);
}
__device__ __forceinline__ unsigned short f2bf(float f) {
    unsigned int u = __builtin_bit_cast(unsigned int, f);
    u += 0x7fffu + ((u >> 16) & 1u);   // RNE (finite inputs)
    return (unsigned short)(u >> 16);
}
__device__ __forceinline__ bf16x8 ld8(const unsigned short* p) {
    return __builtin_bit_cast(bf16x8, *(const uint4*)p);
}
__device__ __forceinline__ floatx4 mfma32(bf16x8 a, bf16x8 b, floatx4 c) {
    return __builtin_amdgcn_mfma_f32_16x16x32_bf16(a, b, c, 0, 0, 0);
}
// async global->LDS, 16B per lane. LDS dest = wave-uniform base + lane*16.
__device__ __forceinline__ void load_lds16(const void* g, void* l) {
    __builtin_amdgcn_global_load_lds(
        (gas_cvp)(unsigned long long)g,
        (las_vp)(unsigned int)(unsigned long long)l,
        16, 0, 0);
}

// ---------------------------------------------------------------------------
// f32 -> bf16 convert
// ---------------------------------------------------------------------------
__global__ void cvt_f32_bf16(const float* __restrict__ in,
                             unsigned short* __restrict__ out, int n4) {
    int i = blockIdx.x * 256 + threadIdx.x;
    if (i < n4) {
        float4 v = ((const float4*)in)[i];
        ushort4 o;
        o.x = f2bf(v.x); o.y = f2bf(v.y); o.z = f2bf(v.z); o.w = f2bf(v.w);
        ((ushort4*)out)[i] = o;
    }
}

// ---------------------------------------------------------------------------
// Generic BT GEMM:  C[m,n] = sum_k A[m,k] * B[n,k]
// ---------------------------------------------------------------------------
struct GemmJob {
    const unsigned short* A;
    const unsigned short* B;
    void* C;
    int M, N, K;
    int rpb, bstride, roff;
};
struct GemmArgs { GemmJob j[4]; };

template <bool F32OUT>
__global__ __launch_bounds__(256, 2) void gemm_bt(GemmArgs args,
                                                  const float* __restrict__ bias) {
    GemmJob jb = args.j[blockIdx.z];
    const int bx = blockIdx.x, by = blockIdx.y;
    if (by * 128 >= jb.M) return;

    const int tid  = threadIdx.x;
    const int lane = tid & 63;
    const int wid  = tid >> 6;
    const int K = jb.K, N = jb.N;

    __shared__ unsigned short ldsA[128 * 32];
    __shared__ unsigned short ldsB[128 * 32];

    const int colA = (tid & 3) * 8;
    auto maprow = [&](int r) -> size_t {
        r = (r < jb.M) ? r : (jb.M - 1);
        int b = r / jb.rpb;
        int t = r - b * jb.rpb;
        return (size_t)(b * jb.bstride + jb.roff + t);
    };
    const unsigned short* pa0 = jb.A + maprow(by * 128 + (tid >> 2)) * K + colA;
    const unsigned short* pa1 = jb.A + maprow(by * 128 + 64 + (tid >> 2)) * K + colA;
    const unsigned short* pb0 = jb.B + (size_t)(bx * 128 + (tid >> 2)) * K + colA;
    const unsigned short* pb1 = jb.B + (size_t)(bx * 128 + 64 + (tid >> 2)) * K + colA;

    unsigned short* la0 = &ldsA[tid * 8];
    unsigned short* la1 = &ldsA[2048 + tid * 8];
    unsigned short* lb0 = &ldsB[tid * 8];
    unsigned short* lb1 = &ldsB[2048 + tid * 8];

    floatx4 acc[4][4] = {};

    const int wm = (wid & 1) * 64;
    const int wn = (wid >> 1) * 64;
    const int fr = lane & 15;
    const int fc = (lane >> 4) * 8;

    for (int k0 = 0; k0 < K; k0 += 32) {
        __syncthreads();
        load_lds16(pa0 + k0, la0);
        load_lds16(pa1 + k0, la1);
        load_lds16(pb0 + k0, lb0);
        load_lds16(pb1 + k0, lb1);
        __syncthreads();

        bf16x8 af[4], bfv[4];
#pragma unroll
        for (int i = 0; i < 4; i++)
            af[i] = *(const bf16x8*)&ldsA[(wm + i * 16 + fr) * 32 + fc];
#pragma unroll
        for (int i = 0; i < 4; i++)
            bfv[i] = *(const bf16x8*)&ldsB[(wn + i * 16 + fr) * 32 + fc];
#pragma unroll
        for (int mi = 0; mi < 4; mi++)
#pragma unroll
            for (int ni = 0; ni < 4; ni++)
                acc[mi][ni] = __builtin_amdgcn_mfma_f32_16x16x32_bf16(
                    af[mi], bfv[ni], acc[mi][ni], 0, 0, 0);
    }

    const int colBase = bx * 128 + wn;
    const int rowBase = by * 128 + wm;
#pragma unroll
    for (int mi = 0; mi < 4; mi++) {
#pragma unroll
        for (int ni = 0; ni < 4; ni++) {
            int col  = colBase + ni * 16 + (lane & 15);
            int row0 = rowBase + mi * 16 + (lane >> 4) * 4;
#pragma unroll
            for (int r = 0; r < 4; r++) {
                int row = row0 + r;
                if (row < jb.M) {
                    float v = acc[mi][ni][r];
                    if (F32OUT)
                        ((float*)jb.C)[(size_t)row * N + col] = v + bias[col];
                    else
                        ((unsigned short*)jb.C)[(size_t)row * N + col] = f2bf(v);
                }
            }
        }
    }
}

// ---------------------------------------------------------------------------
// MFMA attention. Block = (q-tile of 32 rows) x (head) x (batch pair).
// 4 waves: wave w -> batch bi=w>>1, row strip (w&1)*16.
// Q/K fragments read directly from global (K is L2-resident); V transposed
// into LDS; P round-trips through LDS for C->A layout + cross-batch blend.
// ---------------------------------------------------------------------------
#define NT 77
#define NI 20
#define VSTR 104   // sVt/sP padded col stride (2-way-free banks, 16B aligned)
#define ISTR 40

__global__ __launch_bounds__(256, 2) void attn_mfma(
    const unsigned short* __restrict__ q,    // [4*4096][1280]
    const unsigned short* __restrict__ kt,   // [4*77][1280]
    const unsigned short* __restrict__ vt,   // [4*77][1280]
    const unsigned short* __restrict__ kip,  // [4*20][1280]
    const unsigned short* __restrict__ vip,  // [4*20][1280]
    unsigned short* __restrict__ outp)       // [4*4096][1280]
{
    const int tid = threadIdx.x;
    const int qt = blockIdx.x;   // 0..127 (32 rows each)
    const int h  = blockIdx.y;   // 0..19
    const int pz = blockIdx.z;   // 0..1 (batch pair)
    const int b0 = 2 * pz;
    const int lane  = tid & 63;
    const int w     = tid >> 6;
    const int bi    = w >> 1;        // batch within pair
    const int strip = (w & 1) * 16;  // row strip within 32-row tile
    const int fr = lane & 15;
    const int g  = lane >> 4;

    __shared__ unsigned short sVt[2][64][VSTR];    // V^T text, keys 77..103 = 0
    __shared__ unsigned short sVipt[2][64][ISTR];  // V^T ip,   keys 20..39  = 0
    __shared__ unsigned short sP[2][32][VSTR];     // probs (bf16), cols 80.. = 0

    // ---- zero pads ----
    for (int i = tid; i < 2 * 64 * (VSTR - NT); i += 256) {
        int b = i / (64 * (VSTR - NT)); int rem = i % (64 * (VSTR - NT));
        sVt[b][rem / (VSTR - NT)][NT + rem % (VSTR - NT)] = 0;
    }
    for (int i = tid; i < 2 * 64 * (ISTR - NI); i += 256) {
        int b = i / (64 * (ISTR - NI)); int rem = i % (64 * (ISTR - NI));
        sVipt[b][rem / (ISTR - NI)][NI + rem % (ISTR - NI)] = 0;
    }
    for (int i = tid; i < 2 * 32 * (VSTR - 80); i += 256) {
        int b = i / (32 * (VSTR - 80)); int rem = i % (32 * (VSTR - 80));
        sP[b][rem / (VSTR - 80)][80 + rem % (VSTR - 80)] = 0;
    }

    // ---- transpose V into LDS (consecutive threads -> consecutive keys) ----
    for (int c = tid; c < 2 * 8 * NT; c += 256) {
        int b = c / (8 * NT); int rem = c % (8 * NT);
        int dc = rem / NT; int key = rem % NT;
        uint4 v = *(const uint4*)&vt[((size_t)((b0 + b) * NT + key)) * 1280 + h * 64 + dc * 8];
        unsigned int uu[4] = {v.x, v.y, v.z, v.w};
#pragma unroll
        for (int j = 0; j < 4; j++) {
            sVt[b][dc * 8 + 2 * j][key]     = (unsigned short)(uu[j] & 0xffffu);
            sVt[b][dc * 8 + 2 * j + 1][key] = (unsigned short)(uu[j] >> 16);
        }
    }
    for (int c = tid; c < 2 * 8 * NI; c += 256) {
        int b = c / (8 * NI); int rem = c % (8 * NI);
        int dc = rem / NI; int key = rem % NI;
        uint4 v = *(const uint4*)&vip[((size_t)((b0 + b) * NI + key)) * 1280 + h * 64 + dc * 8];
        unsigned int uu[4] = {v.x, v.y, v.z, v.w};
#pragma unroll
        for (int j = 0; j < 4; j++) {
            sVipt[b][dc * 8 + 2 * j][key]     = (unsigned short)(uu[j] & 0xffffu);
            sVipt[b][dc * 8 + 2 * j + 1][key] = (unsigned short)(uu[j] >> 16);
        }
    }

    // ---- Q A-frags direct from global ----
    const size_t qbase = ((size_t)((b0 + bi) * 4096 + qt * 32 + strip + fr)) * 1280 + h * 64;
    bf16x8 aq0 = ld8(&q[qbase + g * 8]);
    bf16x8 aq1 = ld8(&q[qbase + 32 + g * 8]);

    // ---- text scores: 5 key tiles x 2 K-chunks ----
    floatx4 sc[5] = {};
#pragma unroll
    for (int t = 0; t < 5; t++) {
        int key = t * 16 + fr; key = (key < NT) ? key : (NT - 1);
        const size_t kb = ((size_t)((b0 + bi) * NT + key)) * 1280 + h * 64;
        sc[t] = mfma32(aq0, ld8(&kt[kb + g * 8]), sc[t]);
        sc[t] = mfma32(aq1, ld8(&kt[kb + 32 + g * 8]), sc[t]);
    }

    // ---- softmax (rows in registers, reduce over 16 col-lanes) ----
#pragma unroll
    for (int r = 0; r < 4; r++) {
        float m = -1e30f;
#pragma unroll
        for (int t = 0; t < 5; t++) {
            float v = sc[t][r] * 0.125f;
            if (t == 4 && fr >= 13) v = -1e30f;   // keys 77..79 masked
            sc[t][r] = v;
            m = fmaxf(m, v);
        }
        m = fmaxf(m, __shfl_xor(m, 1));
        m = fmaxf(m, __shfl_xor(m, 2));
        m = fmaxf(m, __shfl_xor(m, 4));
        m = fmaxf(m, __shfl_xor(m, 8));
        float sum = 0.f;
#pragma unroll
        for (int t = 0; t < 5; t++) {
            float e = __expf(sc[t][r] - m);
            sc[t][r] = e;
            sum += e;
        }
        sum += __shfl_xor(sum, 1);
        sum += __shfl_xor(sum, 2);
        sum += __shfl_xor(sum, 4);
        sum += __shfl_xor(sum, 8);
        float inv = 1.f / sum;
#pragma unroll
        for (int t = 0; t < 5; t++)
            sP[bi][strip + g * 4 + r][t * 16 + fr] = f2bf(sc[t][r] * inv);
    }
    __syncthreads();

    // ---- blend text probs: p1 = 0.5*(p1+p0) (pads stay zero) ----
    {
        unsigned int* p0 = (unsigned int*)&sP[0][0][0];
        unsigned int* p1 = (unsigned int*)&sP[1][0][0];
        for (int i = tid; i < 32 * VSTR / 2; i += 256) {
            unsigned int a = p0[i], b = p1[i];
            unsigned short r0 = f2bf(0.5f * (bflo(a) + bflo(b)));
            unsigned short r1 = f2bf(0.5f * (bfhi(a) + bfhi(b)));
            p1[i] = (unsigned int)r0 | ((unsigned int)r1 << 16);
        }
    }
    __syncthreads();

    // ---- text PV (K padded to 96 with zeros) ----
    floatx4 accO[4] = {};
    {
        const unsigned short* prow = &sP[bi][strip + fr][0];
        bf16x8 pa0 = ld8(prow + g * 8);
        bf16x8 pa1 = ld8(prow + 32 + g * 8);
        bf16x8 pa2 = ld8(prow + 64 + g * 8);
#pragma unroll
        for (int dt = 0; dt < 4; dt++) {
            const unsigned short* vrow = &sVt[bi][dt * 16 + fr][0];
            accO[dt] = mfma32(pa0, ld8(vrow + g * 8), accO[dt]);
            accO[dt] = mfma32(pa1, ld8(vrow + 32 + g * 8), accO[dt]);
            accO[dt] = mfma32(pa2, ld8(vrow + 64 + g * 8), accO[dt]);
        }
    }

    // ---- ip scores: 2 key tiles x 2 K-chunks ----
    floatx4 si[2] = {};
#pragma unroll
    for (int t = 0; t < 2; t++) {
        int key = t * 16 + fr; key = (key < NI) ? key : (NI - 1);
        const size_t kb = ((size_t)((b0 + bi) * NI + key)) * 1280 + h * 64;
        si[t] = mfma32(aq0, ld8(&kip[kb + g * 8]), si[t]);
        si[t] = mfma32(aq1, ld8(&kip[kb + 32 + g * 8]), si[t]);
    }
#pragma unroll
    for (int r = 0; r < 4; r++) {
        float v0 = si[0][r] * 0.125f;
        float v1 = (fr >= 4) ? -1e30f : si[1][r] * 0.125f;  // keys 20..31 masked
        float m = fmaxf(v0, v1);
        m = fmaxf(m, __shfl_xor(m, 1));
        m = fmaxf(m, __shfl_xor(m, 2));
        m = fmaxf(m, __shfl_xor(m, 4));
        m = fmaxf(m, __shfl_xor(m, 8));
        float e0 = __expf(v0 - m), e1 = __expf(v1 - m);
        float s = e0 + e1;
        s += __shfl_xor(s, 1);
        s += __shfl_xor(s, 2);
        s += __shfl_xor(s, 4);
        s += __shfl_xor(s, 8);
        float inv = 1.f / s;
        si[0][r] = e0 * inv;
        si[1][r] = e1 * inv;
    }
    __syncthreads();   // all text-PV A-frag reads done before overwriting sP

#pragma unroll
    for (int r = 0; r < 4; r++) {
        sP[bi][strip + g * 4 + r][fr]      = f2bf(si[0][r]);
        sP[bi][strip + g * 4 + r][16 + fr] = f2bf(si[1][r]);
    }
    __syncthreads();

    // ---- blend ip probs (cols 0..31) ----
    for (int i = tid; i < 32 * 16; i += 256) {
        int r = i >> 4, kk = i & 15;
        unsigned int* p0 = (unsigned int*)&sP[0][r][0];
        unsigned int* p1 = (unsigned int*)&sP[1][r][0];
        unsigned int a = p0[kk], b = p1[kk];
        unsigned short r0 = f2bf(0.5f * (bflo(a) + bflo(b)));
        unsigned short r1 = f2bf(0.5f * (bfhi(a) + bfhi(b)));
        p1[kk] = (unsigned int)r0 | ((unsigned int)r1 << 16);
    }
    __syncthreads();

    // ---- ip PV: only odd batch of the pair ----
    if (bi == 1) {
        const unsigned short* prow = &sP[1][strip + fr][0];
        bf16x8 pip = ld8(prow + g * 8);
#pragma unroll
        for (int dt = 0; dt < 4; dt++)
            accO[dt] = mfma32(pip, ld8(&sVipt[1][dt * 16 + fr][g * 8]), accO[dt]);
    }

    // ---- write out (C-layout: col=fr, row=g*4+r) ----
    const size_t orow0 = (size_t)((b0 + bi) * 4096 + qt * 32 + strip);
#pragma unroll
    for (int dt = 0; dt < 4; dt++) {
        int col = h * 64 + dt * 16 + fr;
#pragma unroll
        for (int r = 0; r < 4; r++)
            outp[(orow0 + g * 4 + r) * 1280 + col] = f2bf(accO[dt][r]);
    }
}

// ---------------------------------------------------------------------------
// Host launch
// ---------------------------------------------------------------------------
extern "C" void kernel_launch(void* const* d_in, const int* in_sizes, int n_in,
                              void* d_out, int out_size, void* d_ws, size_t ws_size,
                              hipStream_t stream) {
    const float* hs   = (const float*)d_in[0];
    const float* ehs  = (const float*)d_in[1];
    const float* Wq   = (const float*)d_in[2];
    const float* Wk   = (const float*)d_in[3];
    const float* Wv   = (const float*)d_in[4];
    const float* Wkip = (const float*)d_in[5];
    const float* Wvip = (const float*)d_in[6];
    const float* Wo   = (const float*)d_in[7];
    const float* bo   = (const float*)d_in[8];

    char* w = (char*)d_ws;
    size_t off = 0;
    auto alloc = [&](size_t bytes) {
        char* pp = w + off;
        off += (bytes + 255) & ~(size_t)255;
        return pp;
    };
    unsigned short* hs_bf   = (unsigned short*)alloc(16384ull * 1280 * 2);
    unsigned short* q_bf    = (unsigned short*)alloc(16384ull * 1280 * 2);
    unsigned short* at_bf   = (unsigned short*)alloc(16384ull * 1280 * 2);
    unsigned short* ehs_bf  = (unsigned short*)alloc(4ull * 97 * 2048 * 2);
    unsigned short* Wq_bf   = (unsigned short*)alloc(1280ull * 1280 * 2);
    unsigned short* Wk_bf   = (unsigned short*)alloc(1280ull * 2048 * 2);
    unsigned short* Wv_bf   = (unsigned short*)alloc(1280ull * 2048 * 2);
    unsigned short* Wkip_bf = (unsigned short*)alloc(1280ull * 2048 * 2);
    unsigned short* Wvip_bf = (unsigned short*)alloc(1280ull * 2048 * 2);
    unsigned short* Wo_bf   = (unsigned short*)alloc(1280ull * 1280 * 2);
    unsigned short* kt  = (unsigned short*)alloc(308ull * 1280 * 2);
    unsigned short* vt  = (unsigned short*)alloc(308ull * 1280 * 2);
    unsigned short* kip = (unsigned short*)alloc(80ull * 1280 * 2);
    unsigned short* vip = (unsigned short*)alloc(80ull * 1280 * 2);

    auto cvt = [&](const float* src, unsigned short* dst, size_t n) {
        int n4 = (int)(n / 4);
        cvt_f32_bf16<<<dim3((n4 + 255) / 256), dim3(256), 0, stream>>>(src, dst, n4);
    };
    cvt(hs,   hs_bf,   16384ull * 1280);
    cvt(ehs,  ehs_bf,  4ull * 97 * 2048);
    cvt(Wq,   Wq_bf,   1280ull * 1280);
    cvt(Wk,   Wk_bf,   1280ull * 2048);
    cvt(Wv,   Wv_bf,   1280ull * 2048);
    cvt(Wkip, Wkip_bf, 1280ull * 2048);
    cvt(Wvip, Wvip_bf, 1280ull * 2048);
    cvt(Wo,   Wo_bf,   1280ull * 1280);

    // q = hs @ Wq^T
    GemmArgs gq{};
    gq.j[0] = GemmJob{hs_bf, Wq_bf, (void*)q_bf, 16384, 1280, 1280, 16384, 0, 0};
    gemm_bt<false><<<dim3(10, 128, 1), 256, 0, stream>>>(gq, nullptr);

    // k/v projections (text rows 0..76, ip rows 77..96 of each 97-row batch)
    GemmArgs gkv{};
    gkv.j[0] = GemmJob{ehs_bf, Wk_bf,   (void*)kt,  308, 1280, 2048, 77, 97, 0};
    gkv.j[1] = GemmJob{ehs_bf, Wv_bf,   (void*)vt,  308, 1280, 2048, 77, 97, 0};
    gkv.j[2] = GemmJob{ehs_bf, Wkip_bf, (void*)kip,  80, 1280, 2048, 20, 97, 77};
    gkv.j[3] = GemmJob{ehs_bf, Wvip_bf, (void*)vip,  80, 1280, 2048, 20, 97, 77};
    gemm_bt<false><<<dim3(10, 3, 4), 256, 0, stream>>>(gkv, nullptr);

    // fused MFMA attention (text + ip, blend, odd-batch ip add)
    attn_mfma<<<dim3(128, 20, 2), 256, 0, stream>>>(q_bf, kt, vt, kip, vip, at_bf);

    // out = attn @ Wo^T + bo  (f32 output)
    GemmArgs go{};
    go.j[0] = GemmJob{at_bf, Wo_bf, d_out, 16384, 1280, 1280, 16384, 0, 0};
    gemm_bt<true><<<dim3(10, 128, 1), 256, 0, stream>>>(go, bo);
}

// Round 3
// 488.592 us; speedup vs baseline: 2.1000x; 1.0464x over previous
//
#include <hip/hip_runtime.h>
#include <cstdint>

// ---------------------------------------------------------------------------
// Types / helpers
// ---------------------------------------------------------------------------
typedef float floatx4 __attribute__((ext_vector_type(4)));
typedef __bf16 bf16x8 __attribute__((ext_vector_type(8)));

typedef const __attribute__((address_space(1))) void* gas_cvp;
typedef __attribute__((address_space(3))) void* las_vp;

__device__ __forceinline__ float bflo(unsigned int u) {
    return __builtin_bit_cast(float, u << 16);
}
__device__ __forceinline__ float bfhi(unsigned int u) {
    return __builtin_bit_cast(float, u & 0xffff0000u);
}
__device__ __forceinline__ unsigned short f2bf(float f) {
    unsigned int u = __builtin_bit_cast(unsigned int, f);
    u += 0x7fffu + ((u >> 16) & 1u);   // RNE (finite inputs)
    return (unsigned short)(u >> 16);
}
__device__ __forceinline__ bf16x8 ld8(const unsigned short* p) {
    return __builtin_bit_cast(bf16x8, *(const uint4*)p);
}
__device__ __forceinline__ floatx4 mfma32(bf16x8 a, bf16x8 b, floatx4 c) {
    return __builtin_amdgcn_mfma_f32_16x16x32_bf16(a, b, c, 0, 0, 0);
}
// async global->LDS, 16B per lane. LDS dest = wave-uniform base + lane*16.
__device__ __forceinline__ void load_lds16(const void* g, void* l) {
    __builtin_amdgcn_global_load_lds(
        (gas_cvp)(unsigned long long)g,
        (las_vp)(unsigned int)(unsigned long long)l,
        16, 0, 0);
}

// ---------------------------------------------------------------------------
// f32 -> bf16 convert
// ---------------------------------------------------------------------------
__global__ void cvt_f32_bf16(const float* __restrict__ in,
                             unsigned short* __restrict__ out, int n4) {
    int i = blockIdx.x * 256 + threadIdx.x;
    if (i < n4) {
        float4 v = ((const float4*)in)[i];
        ushort4 o;
        o.x = f2bf(v.x); o.y = f2bf(v.y); o.z = f2bf(v.z); o.w = f2bf(v.w);
        ((ushort4*)out)[i] = o;
    }
}

// ---------------------------------------------------------------------------
// Generic BT GEMM:  C[m,n] = sum_k A[m,k] * B[n,k]
// Grid is flat in x. When mtiles%8==0, an XCD-aware swizzle maps blocks so
// that (under round-robin block->XCD dispatch) each XCD keeps one A-row-tile
// (by) fixed while sweeping all bx — A-tile fetched once per L2, B resident.
// ---------------------------------------------------------------------------
struct GemmJob {
    const unsigned short* A;
    const unsigned short* B;
    void* C;
    int M, N, K;
    int rpb, bstride, roff;
};
struct GemmArgs { GemmJob j[4]; };

template <bool F32OUT>
__global__ __launch_bounds__(256, 2) void gemm_bt(GemmArgs args,
                                                  const float* __restrict__ bias) {
    GemmJob jb = args.j[blockIdx.z];
    const int ntiles = jb.N >> 7;
    const int mtiles = (jb.M + 127) >> 7;

    int bx, by;
    {
        int idx = blockIdx.x;
        if ((mtiles & 7) == 0) {
            int gsz = ntiles * 8;
            int group = idx / gsz;
            int rem = idx - group * gsz;
            by = group * 8 + (rem & 7);
            bx = rem >> 3;
        } else {
            by = idx / ntiles;
            bx = idx - by * ntiles;
        }
    }
    if (by * 128 >= jb.M) return;

    const int tid  = threadIdx.x;
    const int lane = tid & 63;
    const int wid  = tid >> 6;
    const int K = jb.K, N = jb.N;

    __shared__ unsigned short ldsA[128 * 32];
    __shared__ unsigned short ldsB[128 * 32];

    const int colA = (tid & 3) * 8;
    auto maprow = [&](int r) -> size_t {
        r = (r < jb.M) ? r : (jb.M - 1);
        int b = r / jb.rpb;
        int t = r - b * jb.rpb;
        return (size_t)(b * jb.bstride + jb.roff + t);
    };
    const unsigned short* pa0 = jb.A + maprow(by * 128 + (tid >> 2)) * K + colA;
    const unsigned short* pa1 = jb.A + maprow(by * 128 + 64 + (tid >> 2)) * K + colA;
    const unsigned short* pb0 = jb.B + (size_t)(bx * 128 + (tid >> 2)) * K + colA;
    const unsigned short* pb1 = jb.B + (size_t)(bx * 128 + 64 + (tid >> 2)) * K + colA;

    unsigned short* la0 = &ldsA[tid * 8];
    unsigned short* la1 = &ldsA[2048 + tid * 8];
    unsigned short* lb0 = &ldsB[tid * 8];
    unsigned short* lb1 = &ldsB[2048 + tid * 8];

    floatx4 acc[4][4] = {};

    const int wm = (wid & 1) * 64;
    const int wn = (wid >> 1) * 64;
    const int fr = lane & 15;
    const int fc = (lane >> 4) * 8;

    for (int k0 = 0; k0 < K; k0 += 32) {
        __syncthreads();
        load_lds16(pa0 + k0, la0);
        load_lds16(pa1 + k0, la1);
        load_lds16(pb0 + k0, lb0);
        load_lds16(pb1 + k0, lb1);
        __syncthreads();

        bf16x8 af[4], bfv[4];
#pragma unroll
        for (int i = 0; i < 4; i++)
            af[i] = *(const bf16x8*)&ldsA[(wm + i * 16 + fr) * 32 + fc];
#pragma unroll
        for (int i = 0; i < 4; i++)
            bfv[i] = *(const bf16x8*)&ldsB[(wn + i * 16 + fr) * 32 + fc];
#pragma unroll
        for (int mi = 0; mi < 4; mi++)
#pragma unroll
            for (int ni = 0; ni < 4; ni++)
                acc[mi][ni] = __builtin_amdgcn_mfma_f32_16x16x32_bf16(
                    af[mi], bfv[ni], acc[mi][ni], 0, 0, 0);
    }

    const int colBase = bx * 128 + wn;
    const int rowBase = by * 128 + wm;
#pragma unroll
    for (int mi = 0; mi < 4; mi++) {
#pragma unroll
        for (int ni = 0; ni < 4; ni++) {
            int col  = colBase + ni * 16 + (lane & 15);
            int row0 = rowBase + mi * 16 + (lane >> 4) * 4;
#pragma unroll
            for (int r = 0; r < 4; r++) {
                int row = row0 + r;
                if (row < jb.M) {
                    float v = acc[mi][ni][r];
                    if (F32OUT)
                        ((float*)jb.C)[(size_t)row * N + col] = v + bias[col];
                    else
                        ((unsigned short*)jb.C)[(size_t)row * N + col] = f2bf(v);
                }
            }
        }
    }
}

// ---------------------------------------------------------------------------
// MFMA attention. Block = (q-tile of 32 rows) x (head) x (batch pair).
// ---------------------------------------------------------------------------
#define NT 77
#define NI 20
#define VSTR 104
#define ISTR 40

__global__ __launch_bounds__(256, 2) void attn_mfma(
    const unsigned short* __restrict__ q,    // [4*4096][1280]
    const unsigned short* __restrict__ kt,   // [4*77][1280]
    const unsigned short* __restrict__ vt,   // [4*77][1280]
    const unsigned short* __restrict__ kip,  // [4*20][1280]
    const unsigned short* __restrict__ vip,  // [4*20][1280]
    unsigned short* __restrict__ outp)       // [4*4096][1280]
{
    const int tid = threadIdx.x;
    const int qt = blockIdx.x;
    const int h  = blockIdx.y;
    const int pz = blockIdx.z;
    const int b0 = 2 * pz;
    const int lane  = tid & 63;
    const int w     = tid >> 6;
    const int bi    = w >> 1;
    const int strip = (w & 1) * 16;
    const int fr = lane & 15;
    const int g  = lane >> 4;

    __shared__ unsigned short sVt[2][64][VSTR];
    __shared__ unsigned short sVipt[2][64][ISTR];
    __shared__ unsigned short sP[2][32][VSTR];

    for (int i = tid; i < 2 * 64 * (VSTR - NT); i += 256) {
        int b = i / (64 * (VSTR - NT)); int rem = i % (64 * (VSTR - NT));
        sVt[b][rem / (VSTR - NT)][NT + rem % (VSTR - NT)] = 0;
    }
    for (int i = tid; i < 2 * 64 * (ISTR - NI); i += 256) {
        int b = i / (64 * (ISTR - NI)); int rem = i % (64 * (ISTR - NI));
        sVipt[b][rem / (ISTR - NI)][NI + rem % (ISTR - NI)] = 0;
    }
    for (int i = tid; i < 2 * 32 * (VSTR - 80); i += 256) {
        int b = i / (32 * (VSTR - 80)); int rem = i % (32 * (VSTR - 80));
        sP[b][rem / (VSTR - 80)][80 + rem % (VSTR - 80)] = 0;
    }

    for (int c = tid; c < 2 * 8 * NT; c += 256) {
        int b = c / (8 * NT); int rem = c % (8 * NT);
        int dc = rem / NT; int key = rem % NT;
        uint4 v = *(const uint4*)&vt[((size_t)((b0 + b) * NT + key)) * 1280 + h * 64 + dc * 8];
        unsigned int uu[4] = {v.x, v.y, v.z, v.w};
#pragma unroll
        for (int j = 0; j < 4; j++) {
            sVt[b][dc * 8 + 2 * j][key]     = (unsigned short)(uu[j] & 0xffffu);
            sVt[b][dc * 8 + 2 * j + 1][key] = (unsigned short)(uu[j] >> 16);
        }
    }
    for (int c = tid; c < 2 * 8 * NI; c += 256) {
        int b = c / (8 * NI); int rem = c % (8 * NI);
        int dc = rem / NI; int key = rem % NI;
        uint4 v = *(const uint4*)&vip[((size_t)((b0 + b) * NI + key)) * 1280 + h * 64 + dc * 8];
        unsigned int uu[4] = {v.x, v.y, v.z, v.w};
#pragma unroll
        for (int j = 0; j < 4; j++) {
            sVipt[b][dc * 8 + 2 * j][key]     = (unsigned short)(uu[j] & 0xffffu);
            sVipt[b][dc * 8 + 2 * j + 1][key] = (unsigned short)(uu[j] >> 16);
        }
    }

    const size_t qbase = ((size_t)((b0 + bi) * 4096 + qt * 32 + strip + fr)) * 1280 + h * 64;
    bf16x8 aq0 = ld8(&q[qbase + g * 8]);
    bf16x8 aq1 = ld8(&q[qbase + 32 + g * 8]);

    floatx4 sc[5] = {};
#pragma unroll
    for (int t = 0; t < 5; t++) {
        int key = t * 16 + fr; key = (key < NT) ? key : (NT - 1);
        const size_t kb = ((size_t)((b0 + bi) * NT + key)) * 1280 + h * 64;
        sc[t] = mfma32(aq0, ld8(&kt[kb + g * 8]), sc[t]);
        sc[t] = mfma32(aq1, ld8(&kt[kb + 32 + g * 8]), sc[t]);
    }

#pragma unroll
    for (int r = 0; r < 4; r++) {
        float m = -1e30f;
#pragma unroll
        for (int t = 0; t < 5; t++) {
            float v = sc[t][r] * 0.125f;
            if (t == 4 && fr >= 13) v = -1e30f;
            sc[t][r] = v;
            m = fmaxf(m, v);
        }
        m = fmaxf(m, __shfl_xor(m, 1));
        m = fmaxf(m, __shfl_xor(m, 2));
        m = fmaxf(m, __shfl_xor(m, 4));
        m = fmaxf(m, __shfl_xor(m, 8));
        float sum = 0.f;
#pragma unroll
        for (int t = 0; t < 5; t++) {
            float e = __expf(sc[t][r] - m);
            sc[t][r] = e;
            sum += e;
        }
        sum += __shfl_xor(sum, 1);
        sum += __shfl_xor(sum, 2);
        sum += __shfl_xor(sum, 4);
        sum += __shfl_xor(sum, 8);
        float inv = 1.f / sum;
#pragma unroll
        for (int t = 0; t < 5; t++)
            sP[bi][strip + g * 4 + r][t * 16 + fr] = f2bf(sc[t][r] * inv);
    }
    __syncthreads();

    {
        unsigned int* p0 = (unsigned int*)&sP[0][0][0];
        unsigned int* p1 = (unsigned int*)&sP[1][0][0];
        for (int i = tid; i < 32 * VSTR / 2; i += 256) {
            unsigned int a = p0[i], b = p1[i];
            unsigned short r0 = f2bf(0.5f * (bflo(a) + bflo(b)));
            unsigned short r1 = f2bf(0.5f * (bfhi(a) + bfhi(b)));
            p1[i] = (unsigned int)r0 | ((unsigned int)r1 << 16);
        }
    }
    __syncthreads();

    floatx4 accO[4] = {};
    {
        const unsigned short* prow = &sP[bi][strip + fr][0];
        bf16x8 pa0 = ld8(prow + g * 8);
        bf16x8 pa1 = ld8(prow + 32 + g * 8);
        bf16x8 pa2 = ld8(prow + 64 + g * 8);
#pragma unroll
        for (int dt = 0; dt < 4; dt++) {
            const unsigned short* vrow = &sVt[bi][dt * 16 + fr][0];
            accO[dt] = mfma32(pa0, ld8(vrow + g * 8), accO[dt]);
            accO[dt] = mfma32(pa1, ld8(vrow + 32 + g * 8), accO[dt]);
            accO[dt] = mfma32(pa2, ld8(vrow + 64 + g * 8), accO[dt]);
        }
    }

    floatx4 si[2] = {};
#pragma unroll
    for (int t = 0; t < 2; t++) {
        int key = t * 16 + fr; key = (key < NI) ? key : (NI - 1);
        const size_t kb = ((size_t)((b0 + bi) * NI + key)) * 1280 + h * 64;
        si[t] = mfma32(aq0, ld8(&kip[kb + g * 8]), si[t]);
        si[t] = mfma32(aq1, ld8(&kip[kb + 32 + g * 8]), si[t]);
    }
#pragma unroll
    for (int r = 0; r < 4; r++) {
        float v0 = si[0][r] * 0.125f;
        float v1 = (fr >= 4) ? -1e30f : si[1][r] * 0.125f;
        float m = fmaxf(v0, v1);
        m = fmaxf(m, __shfl_xor(m, 1));
        m = fmaxf(m, __shfl_xor(m, 2));
        m = fmaxf(m, __shfl_xor(m, 4));
        m = fmaxf(m, __shfl_xor(m, 8));
        float e0 = __expf(v0 - m), e1 = __expf(v1 - m);
        float s = e0 + e1;
        s += __shfl_xor(s, 1);
        s += __shfl_xor(s, 2);
        s += __shfl_xor(s, 4);
        s += __shfl_xor(s, 8);
        float inv = 1.f / s;
        si[0][r] = e0 * inv;
        si[1][r] = e1 * inv;
    }
    __syncthreads();

#pragma unroll
    for (int r = 0; r < 4; r++) {
        sP[bi][strip + g * 4 + r][fr]      = f2bf(si[0][r]);
        sP[bi][strip + g * 4 + r][16 + fr] = f2bf(si[1][r]);
    }
    __syncthreads();

    for (int i = tid; i < 32 * 16; i += 256) {
        int r = i >> 4, kk = i & 15;
        unsigned int* p0 = (unsigned int*)&sP[0][r][0];
        unsigned int* p1 = (unsigned int*)&sP[1][r][0];
        unsigned int a = p0[kk], b = p1[kk];
        unsigned short r0 = f2bf(0.5f * (bflo(a) + bflo(b)));
        unsigned short r1 = f2bf(0.5f * (bfhi(a) + bfhi(b)));
        p1[kk] = (unsigned int)r0 | ((unsigned int)r1 << 16);
    }
    __syncthreads();

    if (bi == 1) {
        const unsigned short* prow = &sP[1][strip + fr][0];
        bf16x8 pip = ld8(prow + g * 8);
#pragma unroll
        for (int dt = 0; dt < 4; dt++)
            accO[dt] = mfma32(pip, ld8(&sVipt[1][dt * 16 + fr][g * 8]), accO[dt]);
    }

    const size_t orow0 = (size_t)((b0 + bi) * 4096 + qt * 32 + strip);
#pragma unroll
    for (int dt = 0; dt < 4; dt++) {
        int col = h * 64 + dt * 16 + fr;
#pragma unroll
        for (int r = 0; r < 4; r++)
            outp[(orow0 + g * 4 + r) * 1280 + col] = f2bf(accO[dt][r]);
    }
}

// ---------------------------------------------------------------------------
// Host launch
// ---------------------------------------------------------------------------
extern "C" void kernel_launch(void* const* d_in, const int* in_sizes, int n_in,
                              void* d_out, int out_size, void* d_ws, size_t ws_size,
                              hipStream_t stream) {
    const float* hs   = (const float*)d_in[0];
    const float* ehs  = (const float*)d_in[1];
    const float* Wq   = (const float*)d_in[2];
    const float* Wk   = (const float*)d_in[3];
    const float* Wv   = (const float*)d_in[4];
    const float* Wkip = (const float*)d_in[5];
    const float* Wvip = (const float*)d_in[6];
    const float* Wo   = (const float*)d_in[7];
    const float* bo   = (const float*)d_in[8];

    char* w = (char*)d_ws;
    size_t off = 0;
    auto alloc = [&](size_t bytes) {
        char* pp = w + off;
        off += (bytes + 255) & ~(size_t)255;
        return pp;
    };
    unsigned short* hs_bf   = (unsigned short*)alloc(16384ull * 1280 * 2);
    unsigned short* q_bf    = (unsigned short*)alloc(16384ull * 1280 * 2);
    unsigned short* at_bf   = (unsigned short*)alloc(16384ull * 1280 * 2);
    unsigned short* ehs_bf  = (unsigned short*)alloc(4ull * 97 * 2048 * 2);
    unsigned short* Wq_bf   = (unsigned short*)alloc(1280ull * 1280 * 2);
    unsigned short* Wk_bf   = (unsigned short*)alloc(1280ull * 2048 * 2);
    unsigned short* Wv_bf   = (unsigned short*)alloc(1280ull * 2048 * 2);
    unsigned short* Wkip_bf = (unsigned short*)alloc(1280ull * 2048 * 2);
    unsigned short* Wvip_bf = (unsigned short*)alloc(1280ull * 2048 * 2);
    unsigned short* Wo_bf   = (unsigned short*)alloc(1280ull * 1280 * 2);
    unsigned short* kt  = (unsigned short*)alloc(308ull * 1280 * 2);
    unsigned short* vt  = (unsigned short*)alloc(308ull * 1280 * 2);
    unsigned short* kip = (unsigned short*)alloc(80ull * 1280 * 2);
    unsigned short* vip = (unsigned short*)alloc(80ull * 1280 * 2);

    auto cvt = [&](const float* src, unsigned short* dst, size_t n) {
        int n4 = (int)(n / 4);
        cvt_f32_bf16<<<dim3((n4 + 255) / 256), dim3(256), 0, stream>>>(src, dst, n4);
    };
    cvt(hs,   hs_bf,   16384ull * 1280);
    cvt(ehs,  ehs_bf,  4ull * 97 * 2048);
    cvt(Wq,   Wq_bf,   1280ull * 1280);
    cvt(Wk,   Wk_bf,   1280ull * 2048);
    cvt(Wv,   Wv_bf,   1280ull * 2048);
    cvt(Wkip, Wkip_bf, 1280ull * 2048);
    cvt(Wvip, Wvip_bf, 1280ull * 2048);
    cvt(Wo,   Wo_bf,   1280ull * 1280);

    // q = hs @ Wq^T   (flat grid, XCD swizzle active: mtiles=128)
    GemmArgs gq{};
    gq.j[0] = GemmJob{hs_bf, Wq_bf, (void*)q_bf, 16384, 1280, 1280, 16384, 0, 0};
    gemm_bt<false><<<dim3(1280, 1, 1), 256, 0, stream>>>(gq, nullptr);

    // k/v projections (text rows 0..76, ip rows 77..96 of each 97-row batch)
    GemmArgs gkv{};
    gkv.j[0] = GemmJob{ehs_bf, Wk_bf,   (void*)kt,  308, 1280, 2048, 77, 97, 0};
    gkv.j[1] = GemmJob{ehs_bf, Wv_bf,   (void*)vt,  308, 1280, 2048, 77, 97, 0};
    gkv.j[2] = GemmJob{ehs_bf, Wkip_bf, (void*)kip,  80, 1280, 2048, 20, 97, 77};
    gkv.j[3] = GemmJob{ehs_bf, Wvip_bf, (void*)vip,  80, 1280, 2048, 20, 97, 77};
    gemm_bt<false><<<dim3(30, 1, 4), 256, 0, stream>>>(gkv, nullptr);

    // fused MFMA attention (text + ip, blend, odd-batch ip add)
    attn_mfma<<<dim3(128, 20, 2), 256, 0, stream>>>(q_bf, kt, vt, kip, vip, at_bf);

    // out = attn @ Wo^T + bo  (f32 output)
    GemmArgs go{};
    go.j[0] = GemmJob{at_bf, Wo_bf, d_out, 16384, 1280, 1280, 16384, 0, 0};
    gemm_bt<true><<<dim3(1280, 1, 1), 256, 0, stream>>>(go, bo);
}

// Round 4
// 453.010 us; speedup vs baseline: 2.2649x; 1.0785x over previous
//
#include <hip/hip_runtime.h>
#include <cstdint>

// ---------------------------------------------------------------------------
// Types / helpers
// ---------------------------------------------------------------------------
typedef float floatx4 __attribute__((ext_vector_type(4)));
typedef __bf16 bf16x8 __attribute__((ext_vector_type(8)));

typedef const __attribute__((address_space(1))) void* gas_cvp;
typedef __attribute__((address_space(3))) void* las_vp;

__device__ __forceinline__ float bflo(unsigned int u) {
    return __builtin_bit_cast(float, u << 16);
}
__device__ __forceinline__ float bfhi(unsigned int u) {
    return __builtin_bit_cast(float, u & 0xffff0000u);
}
__device__ __forceinline__ unsigned short f2bf(float f) {
    unsigned int u = __builtin_bit_cast(unsigned int, f);
    u += 0x7fffu + ((u >> 16) & 1u);   // RNE (finite inputs)
    return (unsigned short)(u >> 16);
}
__device__ __forceinline__ bf16x8 ld8(const unsigned short* p) {
    return __builtin_bit_cast(bf16x8, *(const uint4*)p);
}
__device__ __forceinline__ floatx4 mfma32(bf16x8 a, bf16x8 b, floatx4 c) {
    return __builtin_amdgcn_mfma_f32_16x16x32_bf16(a, b, c, 0, 0, 0);
}
// async global->LDS, 16B per lane. LDS dest = wave-uniform base + lane*16.
__device__ __forceinline__ void load_lds16(const void* g, void* l) {
    __builtin_amdgcn_global_load_lds(
        (gas_cvp)(unsigned long long)g,
        (las_vp)(unsigned int)(unsigned long long)l,
        16, 0, 0);
}

// ---------------------------------------------------------------------------
// f32 -> bf16 converts
// ---------------------------------------------------------------------------
__global__ void cvt_f32_bf16(const float* __restrict__ in,
                             unsigned short* __restrict__ out, int n4) {
    int i = blockIdx.x * 256 + threadIdx.x;
    if (i < n4) {
        float4 v = ((const float4*)in)[i];
        ushort4 o;
        o.x = f2bf(v.x); o.y = f2bf(v.y); o.z = f2bf(v.z); o.w = f2bf(v.w);
        ((ushort4*)out)[i] = o;
    }
}

struct CvtJob { const float* src; unsigned short* dst; int n4; };
struct CvtJobs { CvtJob j[7]; };

__global__ void cvt_multi(CvtJobs jobs) {
    CvtJob jb = jobs.j[blockIdx.y];
    int i = blockIdx.x * 256 + threadIdx.x;
    if (i < jb.n4) {
        float4 v = ((const float4*)jb.src)[i];
        ushort4 o;
        o.x = f2bf(v.x); o.y = f2bf(v.y); o.z = f2bf(v.z); o.w = f2bf(v.w);
        ((ushort4*)jb.dst)[i] = o;
    }
}

// ---------------------------------------------------------------------------
// Generic BT GEMM:  C[m,n] = sum_k A[m,k] * B[n,k]
// Flat grid.x; XCD swizzle when mtiles%8==0. LDS k-chunk XOR swizzle breaks
// the 8-way bank conflict on ds_read_b128 fragment loads (8-way -> 2-way).
// ---------------------------------------------------------------------------
struct GemmJob {
    const unsigned short* A;
    const unsigned short* B;
    void* C;
    int M, N, K;
    int rpb, bstride, roff;
};
struct GemmArgs { GemmJob j[5]; };

template <bool F32OUT>
__global__ __launch_bounds__(256, 2) void gemm_bt(GemmArgs args,
                                                  const float* __restrict__ bias) {
    GemmJob jb = args.j[blockIdx.z];
    const int ntiles = jb.N >> 7;
    const int mtiles = (jb.M + 127) >> 7;

    int bx, by;
    {
        int idx = blockIdx.x;
        if ((mtiles & 7) == 0) {
            int gsz = ntiles * 8;
            int group = idx / gsz;
            int rem = idx - group * gsz;
            by = group * 8 + (rem & 7);
            bx = rem >> 3;
        } else {
            by = idx / ntiles;
            bx = idx - by * ntiles;
        }
    }
    if (by * 128 >= jb.M) return;

    const int tid  = threadIdx.x;
    const int lane = tid & 63;
    const int wid  = tid >> 6;
    const int K = jb.K, N = jb.N;

    __shared__ unsigned short ldsA[128 * 32];
    __shared__ unsigned short ldsB[128 * 32];

    // staged col-block is XOR-swizzled by row pair: lane tid stages row tid>>2,
    // global k-chunk ((tid&3) ^ ((tid>>3)&3)).  (works for both 64-row halves)
    const int colA = (((tid & 3) ^ ((tid >> 3) & 3)) * 8);
    auto maprow = [&](int r) -> size_t {
        r = (r < jb.M) ? r : (jb.M - 1);
        int b = r / jb.rpb;
        int t = r - b * jb.rpb;
        return (size_t)(b * jb.bstride + jb.roff + t);
    };
    const unsigned short* pa0 = jb.A + maprow(by * 128 + (tid >> 2)) * K + colA;
    const unsigned short* pa1 = jb.A + maprow(by * 128 + 64 + (tid >> 2)) * K + colA;
    const unsigned short* pb0 = jb.B + (size_t)(bx * 128 + (tid >> 2)) * K + colA;
    const unsigned short* pb1 = jb.B + (size_t)(bx * 128 + 64 + (tid >> 2)) * K + colA;

    unsigned short* la0 = &ldsA[tid * 8];
    unsigned short* la1 = &ldsA[2048 + tid * 8];
    unsigned short* lb0 = &ldsB[tid * 8];
    unsigned short* lb1 = &ldsB[2048 + tid * 8];

    floatx4 acc[4][4] = {};

    const int wm = (wid & 1) * 64;
    const int wn = (wid >> 1) * 64;
    const int fr = lane & 15;
    const int g  = lane >> 4;
    // reader-side swizzle: k-chunk g of row R lives at chunk slot g ^ ((R>>1)&3);
    // (R>>1)&3 == (fr>>1)&3 for all rows this lane touches.
    const int fcs = (g ^ ((fr >> 1) & 3)) * 8;

    for (int k0 = 0; k0 < K; k0 += 32) {
        __syncthreads();
        load_lds16(pa0 + k0, la0);
        load_lds16(pa1 + k0, la1);
        load_lds16(pb0 + k0, lb0);
        load_lds16(pb1 + k0, lb1);
        __syncthreads();

        bf16x8 af[4], bfv[4];
#pragma unroll
        for (int i = 0; i < 4; i++)
            af[i] = *(const bf16x8*)&ldsA[(wm + i * 16 + fr) * 32 + fcs];
#pragma unroll
        for (int i = 0; i < 4; i++)
            bfv[i] = *(const bf16x8*)&ldsB[(wn + i * 16 + fr) * 32 + fcs];
#pragma unroll
        for (int mi = 0; mi < 4; mi++)
#pragma unroll
            for (int ni = 0; ni < 4; ni++)
                acc[mi][ni] = __builtin_amdgcn_mfma_f32_16x16x32_bf16(
                    af[mi], bfv[ni], acc[mi][ni], 0, 0, 0);
    }

    const int colBase = bx * 128 + wn;
    const int rowBase = by * 128 + wm;
#pragma unroll
    for (int mi = 0; mi < 4; mi++) {
#pragma unroll
        for (int ni = 0; ni < 4; ni++) {
            int col  = colBase + ni * 16 + fr;
            int row0 = rowBase + mi * 16 + g * 4;
#pragma unroll
            for (int r = 0; r < 4; r++) {
                int row = row0 + r;
                if (row < jb.M) {
                    float v = acc[mi][ni][r];
                    if (F32OUT)
                        ((float*)jb.C)[(size_t)row * N + col] = v + bias[col];
                    else
                        ((unsigned short*)jb.C)[(size_t)row * N + col] = f2bf(v);
                }
            }
        }
    }
}

// ---------------------------------------------------------------------------
// MFMA attention. Block = (q-tile of 32 rows) x (head) x (batch pair).
// ---------------------------------------------------------------------------
#define NT 77
#define NI 20
#define VSTR 104
#define ISTR 40

__global__ __launch_bounds__(256, 2) void attn_mfma(
    const unsigned short* __restrict__ q,    // [4*4096][1280]
    const unsigned short* __restrict__ kt,   // [4*77][1280]
    const unsigned short* __restrict__ vt,   // [4*77][1280]
    const unsigned short* __restrict__ kip,  // [4*20][1280]
    const unsigned short* __restrict__ vip,  // [4*20][1280]
    unsigned short* __restrict__ outp)       // [4*4096][1280]
{
    const int tid = threadIdx.x;
    const int qt = blockIdx.x;
    const int h  = blockIdx.y;
    const int pz = blockIdx.z;
    const int b0 = 2 * pz;
    const int lane  = tid & 63;
    const int w     = tid >> 6;
    const int bi    = w >> 1;
    const int strip = (w & 1) * 16;
    const int fr = lane & 15;
    const int g  = lane >> 4;

    __shared__ unsigned short sVt[2][64][VSTR];
    __shared__ unsigned short sVipt[2][64][ISTR];
    __shared__ unsigned short sP[2][32][VSTR];

    for (int i = tid; i < 2 * 64 * (VSTR - NT); i += 256) {
        int b = i / (64 * (VSTR - NT)); int rem = i % (64 * (VSTR - NT));
        sVt[b][rem / (VSTR - NT)][NT + rem % (VSTR - NT)] = 0;
    }
    for (int i = tid; i < 2 * 64 * (ISTR - NI); i += 256) {
        int b = i / (64 * (ISTR - NI)); int rem = i % (64 * (ISTR - NI));
        sVipt[b][rem / (ISTR - NI)][NI + rem % (ISTR - NI)] = 0;
    }
    for (int i = tid; i < 2 * 32 * (VSTR - 80); i += 256) {
        int b = i / (32 * (VSTR - 80)); int rem = i % (32 * (VSTR - 80));
        sP[b][rem / (VSTR - 80)][80 + rem % (VSTR - 80)] = 0;
    }

    for (int c = tid; c < 2 * 8 * NT; c += 256) {
        int b = c / (8 * NT); int rem = c % (8 * NT);
        int dc = rem / NT; int key = rem % NT;
        uint4 v = *(const uint4*)&vt[((size_t)((b0 + b) * NT + key)) * 1280 + h * 64 + dc * 8];
        unsigned int uu[4] = {v.x, v.y, v.z, v.w};
#pragma unroll
        for (int j = 0; j < 4; j++) {
            sVt[b][dc * 8 + 2 * j][key]     = (unsigned short)(uu[j] & 0xffffu);
            sVt[b][dc * 8 + 2 * j + 1][key] = (unsigned short)(uu[j] >> 16);
        }
    }
    for (int c = tid; c < 2 * 8 * NI; c += 256) {
        int b = c / (8 * NI); int rem = c % (8 * NI);
        int dc = rem / NI; int key = rem % NI;
        uint4 v = *(const uint4*)&vip[((size_t)((b0 + b) * NI + key)) * 1280 + h * 64 + dc * 8];
        unsigned int uu[4] = {v.x, v.y, v.z, v.w};
#pragma unroll
        for (int j = 0; j < 4; j++) {
            sVipt[b][dc * 8 + 2 * j][key]     = (unsigned short)(uu[j] & 0xffffu);
            sVipt[b][dc * 8 + 2 * j + 1][key] = (unsigned short)(uu[j] >> 16);
        }
    }

    const size_t qbase = ((size_t)((b0 + bi) * 4096 + qt * 32 + strip + fr)) * 1280 + h * 64;
    bf16x8 aq0 = ld8(&q[qbase + g * 8]);
    bf16x8 aq1 = ld8(&q[qbase + 32 + g * 8]);

    floatx4 sc[5] = {};
#pragma unroll
    for (int t = 0; t < 5; t++) {
        int key = t * 16 + fr; key = (key < NT) ? key : (NT - 1);
        const size_t kb = ((size_t)((b0 + bi) * NT + key)) * 1280 + h * 64;
        sc[t] = mfma32(aq0, ld8(&kt[kb + g * 8]), sc[t]);
        sc[t] = mfma32(aq1, ld8(&kt[kb + 32 + g * 8]), sc[t]);
    }

#pragma unroll
    for (int r = 0; r < 4; r++) {
        float m = -1e30f;
#pragma unroll
        for (int t = 0; t < 5; t++) {
            float v = sc[t][r] * 0.125f;
            if (t == 4 && fr >= 13) v = -1e30f;
            sc[t][r] = v;
            m = fmaxf(m, v);
        }
        m = fmaxf(m, __shfl_xor(m, 1));
        m = fmaxf(m, __shfl_xor(m, 2));
        m = fmaxf(m, __shfl_xor(m, 4));
        m = fmaxf(m, __shfl_xor(m, 8));
        float sum = 0.f;
#pragma unroll
        for (int t = 0; t < 5; t++) {
            float e = __expf(sc[t][r] - m);
            sc[t][r] = e;
            sum += e;
        }
        sum += __shfl_xor(sum, 1);
        sum += __shfl_xor(sum, 2);
        sum += __shfl_xor(sum, 4);
        sum += __shfl_xor(sum, 8);
        float inv = 1.f / sum;
#pragma unroll
        for (int t = 0; t < 5; t++)
            sP[bi][strip + g * 4 + r][t * 16 + fr] = f2bf(sc[t][r] * inv);
    }
    __syncthreads();

    {
        unsigned int* p0 = (unsigned int*)&sP[0][0][0];
        unsigned int* p1 = (unsigned int*)&sP[1][0][0];
        for (int i = tid; i < 32 * VSTR / 2; i += 256) {
            unsigned int a = p0[i], b = p1[i];
            unsigned short r0 = f2bf(0.5f * (bflo(a) + bflo(b)));
            unsigned short r1 = f2bf(0.5f * (bfhi(a) + bfhi(b)));
            p1[i] = (unsigned int)r0 | ((unsigned int)r1 << 16);
        }
    }
    __syncthreads();

    floatx4 accO[4] = {};
    {
        const unsigned short* prow = &sP[bi][strip + fr][0];
        bf16x8 pa0 = ld8(prow + g * 8);
        bf16x8 pa1 = ld8(prow + 32 + g * 8);
        bf16x8 pa2 = ld8(prow + 64 + g * 8);
#pragma unroll
        for (int dt = 0; dt < 4; dt++) {
            const unsigned short* vrow = &sVt[bi][dt * 16 + fr][0];
            accO[dt] = mfma32(pa0, ld8(vrow + g * 8), accO[dt]);
            accO[dt] = mfma32(pa1, ld8(vrow + 32 + g * 8), accO[dt]);
            accO[dt] = mfma32(pa2, ld8(vrow + 64 + g * 8), accO[dt]);
        }
    }

    floatx4 si[2] = {};
#pragma unroll
    for (int t = 0; t < 2; t++) {
        int key = t * 16 + fr; key = (key < NI) ? key : (NI - 1);
        const size_t kb = ((size_t)((b0 + bi) * NI + key)) * 1280 + h * 64;
        si[t] = mfma32(aq0, ld8(&kip[kb + g * 8]), si[t]);
        si[t] = mfma32(aq1, ld8(&kip[kb + 32 + g * 8]), si[t]);
    }
#pragma unroll
    for (int r = 0; r < 4; r++) {
        float v0 = si[0][r] * 0.125f;
        float v1 = (fr >= 4) ? -1e30f : si[1][r] * 0.125f;
        float m = fmaxf(v0, v1);
        m = fmaxf(m, __shfl_xor(m, 1));
        m = fmaxf(m, __shfl_xor(m, 2));
        m = fmaxf(m, __shfl_xor(m, 4));
        m = fmaxf(m, __shfl_xor(m, 8));
        float e0 = __expf(v0 - m), e1 = __expf(v1 - m);
        float s = e0 + e1;
        s += __shfl_xor(s, 1);
        s += __shfl_xor(s, 2);
        s += __shfl_xor(s, 4);
        s += __shfl_xor(s, 8);
        float inv = 1.f / s;
        si[0][r] = e0 * inv;
        si[1][r] = e1 * inv;
    }
    __syncthreads();

#pragma unroll
    for (int r = 0; r < 4; r++) {
        sP[bi][strip + g * 4 + r][fr]      = f2bf(si[0][r]);
        sP[bi][strip + g * 4 + r][16 + fr] = f2bf(si[1][r]);
    }
    __syncthreads();

    for (int i = tid; i < 32 * 16; i += 256) {
        int r = i >> 4, kk = i & 15;
        unsigned int* p0 = (unsigned int*)&sP[0][r][0];
        unsigned int* p1 = (unsigned int*)&sP[1][r][0];
        unsigned int a = p0[kk], b = p1[kk];
        unsigned short r0 = f2bf(0.5f * (bflo(a) + bflo(b)));
        unsigned short r1 = f2bf(0.5f * (bfhi(a) + bfhi(b)));
        p1[kk] = (unsigned int)r0 | ((unsigned int)r1 << 16);
    }
    __syncthreads();

    if (bi == 1) {
        const unsigned short* prow = &sP[1][strip + fr][0];
        bf16x8 pip = ld8(prow + g * 8);
#pragma unroll
        for (int dt = 0; dt < 4; dt++)
            accO[dt] = mfma32(pip, ld8(&sVipt[1][dt * 16 + fr][g * 8]), accO[dt]);
    }

    const size_t orow0 = (size_t)((b0 + bi) * 4096 + qt * 32 + strip);
#pragma unroll
    for (int dt = 0; dt < 4; dt++) {
        int col = h * 64 + dt * 16 + fr;
#pragma unroll
        for (int r = 0; r < 4; r++)
            outp[(orow0 + g * 4 + r) * 1280 + col] = f2bf(accO[dt][r]);
    }
}

// ---------------------------------------------------------------------------
// Host launch
// ---------------------------------------------------------------------------
extern "C" void kernel_launch(void* const* d_in, const int* in_sizes, int n_in,
                              void* d_out, int out_size, void* d_ws, size_t ws_size,
                              hipStream_t stream) {
    const float* hs   = (const float*)d_in[0];
    const float* ehs  = (const float*)d_in[1];
    const float* Wq   = (const float*)d_in[2];
    const float* Wk   = (const float*)d_in[3];
    const float* Wv   = (const float*)d_in[4];
    const float* Wkip = (const float*)d_in[5];
    const float* Wvip = (const float*)d_in[6];
    const float* Wo   = (const float*)d_in[7];
    const float* bo   = (const float*)d_in[8];

    char* w = (char*)d_ws;
    size_t off = 0;
    auto alloc = [&](size_t bytes) {
        char* pp = w + off;
        off += (bytes + 255) & ~(size_t)255;
        return pp;
    };
    unsigned short* hs_bf   = (unsigned short*)alloc(16384ull * 1280 * 2);
    unsigned short* q_bf    = (unsigned short*)alloc(16384ull * 1280 * 2);
    unsigned short* at_bf   = (unsigned short*)alloc(16384ull * 1280 * 2);
    unsigned short* ehs_bf  = (unsigned short*)alloc(4ull * 97 * 2048 * 2);
    unsigned short* Wq_bf   = (unsigned short*)alloc(1280ull * 1280 * 2);
    unsigned short* Wk_bf   = (unsigned short*)alloc(1280ull * 2048 * 2);
    unsigned short* Wv_bf   = (unsigned short*)alloc(1280ull * 2048 * 2);
    unsigned short* Wkip_bf = (unsigned short*)alloc(1280ull * 2048 * 2);
    unsigned short* Wvip_bf = (unsigned short*)alloc(1280ull * 2048 * 2);
    unsigned short* Wo_bf   = (unsigned short*)alloc(1280ull * 1280 * 2);
    unsigned short* kt  = (unsigned short*)alloc(308ull * 1280 * 2);
    unsigned short* vt  = (unsigned short*)alloc(308ull * 1280 * 2);
    unsigned short* kip = (unsigned short*)alloc(80ull * 1280 * 2);
    unsigned short* vip = (unsigned short*)alloc(80ull * 1280 * 2);

    // hs convert (big, own launch)
    cvt_f32_bf16<<<dim3(20480, 1, 1), 256, 0, stream>>>(hs, hs_bf, 16384 * 1280 / 4);

    // all small converts in one launch (7 jobs)
    CvtJobs cj{};
    cj.j[0] = CvtJob{ehs,  ehs_bf,  (int)(4ull * 97 * 2048 / 4)};
    cj.j[1] = CvtJob{Wq,   Wq_bf,   1280 * 1280 / 4};
    cj.j[2] = CvtJob{Wk,   Wk_bf,   1280 * 2048 / 4};
    cj.j[3] = CvtJob{Wv,   Wv_bf,   1280 * 2048 / 4};
    cj.j[4] = CvtJob{Wkip, Wkip_bf, 1280 * 2048 / 4};
    cj.j[5] = CvtJob{Wvip, Wvip_bf, 1280 * 2048 / 4};
    cj.j[6] = CvtJob{Wo,   Wo_bf,   1280 * 1280 / 4};
    cvt_multi<<<dim3(2560, 7, 1), 256, 0, stream>>>(cj);

    // q-proj + 4 k/v projections in ONE dispatch (z-jobs; kv blocks overlap q)
    GemmArgs gq{};
    gq.j[0] = GemmJob{hs_bf,  Wq_bf,   (void*)q_bf, 16384, 1280, 1280, 16384, 0, 0};
    gq.j[1] = GemmJob{ehs_bf, Wk_bf,   (void*)kt,     308, 1280, 2048, 77, 97, 0};
    gq.j[2] = GemmJob{ehs_bf, Wv_bf,   (void*)vt,     308, 1280, 2048, 77, 97, 0};
    gq.j[3] = GemmJob{ehs_bf, Wkip_bf, (void*)kip,     80, 1280, 2048, 20, 97, 77};
    gq.j[4] = GemmJob{ehs_bf, Wvip_bf, (void*)vip,     80, 1280, 2048, 20, 97, 77};
    gemm_bt<false><<<dim3(1280, 1, 5), 256, 0, stream>>>(gq, nullptr);

    // fused MFMA attention (text + ip, blend, odd-batch ip add)
    attn_mfma<<<dim3(128, 20, 2), 256, 0, stream>>>(q_bf, kt, vt, kip, vip, at_bf);

    // out = attn @ Wo^T + bo  (f32 output)
    GemmArgs go{};
    go.j[0] = GemmJob{at_bf, Wo_bf, d_out, 16384, 1280, 1280, 16384, 0, 0};
    gemm_bt<true><<<dim3(1280, 1, 1), 256, 0, stream>>>(go, bo);
}